// Round 3
// baseline (60.152 us; speedup 1.0000x reference)
//
#include <hip/hip_runtime.h>

// BootstrapLoss: mean of the top-20% per-pixel (channel-mean) squared errors.
// input/target: [64, 3, 256, 256] fp32. N_pix = 64*256*256 = 4194304.
// k = N - int(0.8*N) = 838861 largest; output = their mean (scalar f32).
//
// Single-pass histogram selection on the float bit pattern (non-negative
// floats order like their uint32 bit patterns). 4096 bins = sign+exp+4
// mantissa bits (bits>>19). Per bin: COUNT and SUM; the threshold bin's
// partial contribution uses the bin average (error ~ c_b*width/(8k) ~ 40,
// measured 0.0 vs tolerance 448).
//
// R2 lesson: VGPR=44 meant only ~6 loads in flight -> 4 dependent latency
// stalls/thread, latency-bound at 2.4 TB/s. This version issues all 24
// independent float4 loads before any use (explicit unrolled arrays,
// launch_bounds(256,4) -> VGPR cap 128, still 16 waves/CU = grid cap).

#define NPIX   (64 * 256 * 256)   // 4194304
#define NV4    (NPIX / 4)         // 1048576
#define HW     65536
#define CHW    196608
#define KTAIL  838861             // 4194304 - int(0.8 * 4194304)
#define NBIN   4096

__device__ inline float sqf(float x) { return x * x; }

// 1024 blocks x 256 threads x 4 unrolled vec4 iters = NV4 exactly.
__global__ __launch_bounds__(256, 4)
void k_main(const float4* __restrict__ in, const float4* __restrict__ tg,
            unsigned* __restrict__ gcnt, double* __restrict__ gsum) {
  __shared__ unsigned h[NBIN];
  __shared__ float fs[NBIN];
  for (int i = threadIdx.x; i < NBIN; i += 256) { h[i] = 0u; fs[i] = 0.0f; }
  __syncthreads();

  const int t0 = blockIdx.x * 1024 + threadIdx.x;

  // ---- load phase: 24 independent float4 loads, all issued before any use
  float4 a[4][3], b[4][3];
#pragma unroll
  for (int u = 0; u < 4; ++u) {
    int i  = t0 + u * 256;       // vec4 index
    int p  = i << 2;             // pixel index
    int bb = p >> 16;            // batch  (p / HW)
    int hw = p & (HW - 1);
    int base4 = (bb * CHW + hw) >> 2;
    a[u][0] = in[base4];
    a[u][1] = in[base4 + HW / 4];
    a[u][2] = in[base4 + HW / 2];
    b[u][0] = tg[base4];
    b[u][1] = tg[base4 + HW / 4];
    b[u][2] = tg[base4 + HW / 2];
  }

  // ---- compute + LDS histogram phase
  const float S = 65025.0f / 3.0f;   // (255^2)/3
#pragma unroll
  for (int u = 0; u < 4; ++u) {
    float vv[4];
    vv[0] = (sqf(a[u][0].x - b[u][0].x) + sqf(a[u][1].x - b[u][1].x) + sqf(a[u][2].x - b[u][2].x)) * S;
    vv[1] = (sqf(a[u][0].y - b[u][0].y) + sqf(a[u][1].y - b[u][1].y) + sqf(a[u][2].y - b[u][2].y)) * S;
    vv[2] = (sqf(a[u][0].z - b[u][0].z) + sqf(a[u][1].z - b[u][1].z) + sqf(a[u][2].z - b[u][2].z)) * S;
    vv[3] = (sqf(a[u][0].w - b[u][0].w) + sqf(a[u][1].w - b[u][1].w) + sqf(a[u][2].w - b[u][2].w)) * S;
#pragma unroll
    for (int c = 0; c < 4; ++c) {
      unsigned bin = __float_as_uint(vv[c]) >> 19;
      atomicAdd(&h[bin], 1u);
      atomicAdd(&fs[bin], vv[c]);
    }
  }
  __syncthreads();

  // ---- flush block-private histogram to global
  for (int i = threadIdx.x; i < NBIN; i += 256) {
    unsigned c = h[i];
    if (c) {
      atomicAdd(&gcnt[i], c);
      atomicAdd(&gsum[i], (double)fs[i]);
    }
  }
}

__global__ void k_final(const unsigned* __restrict__ gcnt,
                        const double* __restrict__ gsum,
                        float* __restrict__ out) {
  __shared__ unsigned h[NBIN];
  __shared__ double s[NBIN];
  __shared__ unsigned cc[256];
  __shared__ double cs[256];
  const int t = threadIdx.x;
  unsigned lc = 0u;
  double ls = 0.0;
  for (int j = 0; j < 16; ++j) {
    int idx = t * 16 + j;
    unsigned c = gcnt[idx];
    double d = gsum[idx];
    h[idx] = c;
    s[idx] = d;
    lc += c;
    ls += d;
  }
  cc[t] = lc;
  cs[t] = ls;
  __syncthreads();
  if (t == 0) {
    long cum = 0;
    double above = 0.0;
    int chunk = 255;
    for (; chunk > 0; --chunk) {
      if (cum + (long)cc[chunk] >= (long)KTAIL) break;
      cum += cc[chunk];
      above += cs[chunk];
    }
    int b = chunk * 16 + 15;
    for (; b > 0; --b) {
      unsigned c = h[b];
      if (cum + (long)c >= (long)KTAIL) break;
      cum += c;
      above += s[b];
    }
    long r = (long)KTAIL - cum;
    unsigned cb = h[b];
    double avg = cb ? s[b] / (double)cb : 0.0;
    out[0] = (float)((above + (double)r * avg) / (double)KTAIL);
  }
}

extern "C" void kernel_launch(void* const* d_in, const int* in_sizes, int n_in,
                              void* d_out, int out_size, void* d_ws, size_t ws_size,
                              hipStream_t stream) {
  (void)in_sizes; (void)n_in; (void)out_size; (void)ws_size;
  const float4* in = (const float4*)d_in[0];
  const float4* tg = (const float4*)d_in[1];
  float* out = (float*)d_out;
  char* ws = (char*)d_ws;

  unsigned* gcnt = (unsigned*)ws;                  // 16 KB
  double*   gsum = (double*)(ws + NBIN * 4);       // 32 KB (8-aligned)

  // zero accumulators every call (harness does not re-poison between replays)
  hipMemsetAsync(gcnt, 0, NBIN * 4 + NBIN * 8, stream);

  k_main<<<dim3(1024), dim3(256), 0, stream>>>(in, tg, gcnt, gsum);
  k_final<<<1, 256, 0, stream>>>(gcnt, gsum, out);
}